// Round 12
// baseline (216.094 us; speedup 1.0000x reference)
//
#include <hip/hip_runtime.h>
#include <hip/hip_fp16.h>

#define DD 128
#define BK_SHIFT 6
#define BK_NODES 64    // nodes per bucket
#define NBLK 256       // edge-chunk blocks for binning
#define SCAN_T 1024
#define SCAN_E 8
#define SCAN_CHUNK (SCAN_T * SCAN_E)   // 8192

typedef __attribute__((ext_vector_type(8))) _Float16 f16x8;
typedef __attribute__((ext_vector_type(4))) float f32x4;

union h8u { f16x8 v; int i[4]; };

static __device__ __forceinline__ f16x8 vmax8(f16x8 a, f16x8 b) {
#pragma unroll
    for (int i = 0; i < 8; ++i) a[i] = a[i] > b[i] ? a[i] : b[i];
    return a;
}

// ---------------- weights -> fp16, pre-swizzled for LDS bank-conflict-free reads ----
__global__ void prep_w(const float* __restrict__ W0, const float* __restrict__ W1,
                       const float* __restrict__ W2, const float* __restrict__ W3,
                       const float* __restrict__ W4, const float* __restrict__ W5,
                       __half* __restrict__ Wh) {
    int idx = blockIdx.x * 256 + threadIdx.x;   // 0 .. 6*16384-1
    int wi = idx >> 14;
    int off = idx & 16383;
    int j = off >> 7;
    int k = off & 127;
    float a;
    switch (wi) {
        case 0: a = W0[off]; break;
        case 1: a = W1[off]; break;
        case 2: a = W2[off]; break;
        case 3: a = W3[off]; break;
        case 4: a = W4[off]; break;
        default: a = W5[off]; break;
    }
    int k2 = k ^ ((j & 7) << 3);
    Wh[(size_t)wi * 16384 + j * DD + k2] = __float2half(a);
}

// ---------------- x (f32) -> fp16, vectorized ----------------
__global__ void prep_x(const float* __restrict__ x, __half* __restrict__ xh, int n8) {
    int i = blockIdx.x * 256 + threadIdx.x;
    if (i >= n8) return;
    float4 u0 = *(const float4*)(x + (size_t)i * 8);
    float4 u1 = *(const float4*)(x + (size_t)i * 8 + 4);
    f16x8 v;
    v[0] = (_Float16)u0.x; v[1] = (_Float16)u0.y; v[2] = (_Float16)u0.z; v[3] = (_Float16)u0.w;
    v[4] = (_Float16)u1.x; v[5] = (_Float16)u1.y; v[6] = (_Float16)u1.z; v[7] = (_Float16)u1.w;
    *(f16x8*)(xh + (size_t)i * 8) = v;
}

// ---------------- generic per-(bucket,block) histogram of key>>6, LDS only ----------------
__global__ __launch_bounds__(256) void hist2d_kernel(const int* __restrict__ key,
                                                     int* __restrict__ hist2d,
                                                     int E, int NB, int chunk) {
    extern __shared__ int h[];   // NB ints
    int t = threadIdx.x, b = blockIdx.x;
    for (int i = t; i < NB; i += 256) h[i] = 0;
    __syncthreads();
    int e0 = b * chunk, e1 = min(e0 + chunk, E);
    for (int e = e0 + t; e < e1; e += 256)
        atomicAdd(&h[key[e] >> BK_SHIFT], 1);
    __syncthreads();
    for (int i = t; i < NB; i += 256) hist2d[i * NBLK + b] = h[i];
}

// ---------------- multi-block exclusive scan, in place ----------------
__global__ __launch_bounds__(SCAN_T) void partial_reduce(const int* __restrict__ data,
                                                         int* __restrict__ bsum, int n) {
    __shared__ int s[SCAN_T];
    int t = threadIdx.x;
    int i0 = blockIdx.x * SCAN_CHUNK + t * SCAN_E;
    int sum = 0;
#pragma unroll
    for (int u = 0; u < SCAN_E; ++u) {
        int i = i0 + u;
        sum += (i < n) ? data[i] : 0;
    }
    s[t] = sum;
    __syncthreads();
    for (int off = SCAN_T / 2; off > 0; off >>= 1) {
        if (t < off) s[t] += s[t + off];
        __syncthreads();
    }
    if (t == 0) bsum[blockIdx.x] = s[0];
}

__global__ __launch_bounds__(SCAN_T) void scan_excl_inplace(int* __restrict__ data,
                                                            const int* __restrict__ bsum, int n) {
    __shared__ int s[SCAN_T];
    int t = threadIdx.x;
    int b = blockIdx.x;
    int carry = 0;
    for (int k = 0; k < b; ++k) carry += bsum[k];   // few blocks; cheap, uniform
    int i0 = b * SCAN_CHUNK + t * SCAN_E;
    int v[SCAN_E];
    int sum = 0;
#pragma unroll
    for (int u = 0; u < SCAN_E; ++u) {
        v[u] = (i0 + u < n) ? data[i0 + u] : 0;
        sum += v[u];
    }
    s[t] = sum;
    __syncthreads();
    for (int off = 1; off < SCAN_T; off <<= 1) {
        int x = (t >= off) ? s[t - off] : 0;
        __syncthreads();
        s[t] += x;
        __syncthreads();
    }
    int run = s[t] - sum + carry;   // exclusive prefix of this thread's first elem
#pragma unroll
    for (int u = 0; u < SCAN_E; ++u) {
        int i = i0 + u;
        if (i < n) {
            data[i] = run;
            run += v[u];
        }
    }
}

// ---------------- phase A: bin edge PAIRS by src bucket (approx src-sort) ----------------
__global__ __launch_bounds__(256) void bin_src(const int* __restrict__ src,
                                               const int* __restrict__ dst,
                                               const int* __restrict__ base,   // scanned hist2dA
                                               int* __restrict__ es2, int* __restrict__ ed2,
                                               int E, int NB, int chunk) {
    extern __shared__ int h[];   // NB cursors
    int t = threadIdx.x, b = blockIdx.x;
    for (int i = t; i < NB; i += 256) h[i] = base[i * NBLK + b];
    __syncthreads();
    int e0 = b * chunk, e1 = min(e0 + chunk, E);
    for (int e = e0 + t; e < e1; e += 256) {
        int s = src[e];
        int p = atomicAdd(&h[s >> BK_SHIFT], 1);
        es2[p] = s;
        ed2[p] = dst[e];
    }
}

// ---------------- phase B: bin (src-ordered) edges by dst bucket ----------------
__global__ __launch_bounds__(256) void bin_edges2(const int* __restrict__ src,
                                                  const int* __restrict__ dst,
                                                  const int* __restrict__ base,   // scanned hist2dB
                                                  unsigned* __restrict__ ebuf,
                                                  int E, int NB, int chunk) {
    extern __shared__ int h[];   // NB cursors
    int t = threadIdx.x, b = blockIdx.x;
    for (int i = t; i < NB; i += 256) h[i] = base[i * NBLK + b];
    __syncthreads();
    int e0 = b * chunk, e1 = min(e0 + chunk, E);
    for (int e = e0 + t; e < e1; e += 256) {
        int d = dst[e];
        int p = atomicAdd(&h[d >> BK_SHIFT], 1);
        ebuf[p] = ((unsigned)src[e] << BK_SHIFT) | (unsigned)(d & (BK_NODES - 1));
    }
}

// ---------------- per-bucket rowptr + csr scatter ----------------
__global__ __launch_bounds__(256) void build_csr(const unsigned* __restrict__ ebuf,
                                                 const int* __restrict__ base,
                                                 int* __restrict__ rowptr,
                                                 int* __restrict__ csr_src, int N, int NB, int E) {
    __shared__ int cnt[BK_NODES];
    __shared__ int cur[BK_NODES];
    int b = blockIdx.x;
    int t = threadIdx.x;
    int beg = base[b * NBLK];
    int end = (b == NB - 1) ? E : base[(b + 1) * NBLK];
    if (b == 0 && t == 0) rowptr[0] = 0;
    if (t < BK_NODES) cnt[t] = 0;
    __syncthreads();
    for (int e = beg + t; e < end; e += 256)
        atomicAdd(&cnt[ebuf[e] & (BK_NODES - 1)], 1);
    __syncthreads();
    if (t < 64) {   // one wave: scan 64 counts
        int v = cnt[t];
        int inc = v;
#pragma unroll
        for (int off = 1; off < 64; off <<= 1) {
            int x = __shfl_up(inc, off);
            if (t >= off) inc += x;
        }
        cur[t] = beg + inc - v;          // exclusive
        int node = b * BK_NODES + t;
        if (node < N) rowptr[node + 1] = beg + inc;
    }
    __syncthreads();
    for (int e = beg + t; e < end; e += 256) {
        unsigned v = ebuf[e];
        int p = atomicAdd(&cur[v & (BK_NODES - 1)], 1);
        csr_src[p] = (int)(v >> BK_SHIFT);
    }
}

// ---------------- segment max gather v2: 4 edge-subgroups x 16 col-chunks ----------------
__global__ __launch_bounds__(256) void segmax2(const __half* __restrict__ m,
                                               const int* __restrict__ rowptr,
                                               const int* __restrict__ csr_src,
                                               __half* __restrict__ agg, int n) {
    int node = blockIdx.x * 4 + (threadIdx.x >> 6);
    if (node >= n) return;
    int lane = threadIdx.x & 63;
    int g = lane >> 4;
    int l = lane & 15;
    int beg = rowptr[node], end = rowptr[node + 1];
    const __half* mp = m + l * 8;

    f16x8 acc0 = (f16x8)0, acc1 = (f16x8)0, acc2 = (f16x8)0, acc3 = (f16x8)0;  // relu'd >= 0

    int e = beg + g;
    for (; e + 12 < end; e += 16) {
        int s0 = csr_src[e];
        int s1 = csr_src[e + 4];
        int s2 = csr_src[e + 8];
        int s3 = csr_src[e + 12];
        f16x8 u0 = *(const f16x8*)(mp + (size_t)s0 * DD);
        f16x8 u1 = *(const f16x8*)(mp + (size_t)s1 * DD);
        f16x8 u2 = *(const f16x8*)(mp + (size_t)s2 * DD);
        f16x8 u3 = *(const f16x8*)(mp + (size_t)s3 * DD);
        acc0 = vmax8(acc0, u0);
        acc1 = vmax8(acc1, u1);
        acc2 = vmax8(acc2, u2);
        acc3 = vmax8(acc3, u3);
    }
    for (; e < end; e += 4) {
        int s0 = csr_src[e];
        f16x8 u0 = *(const f16x8*)(mp + (size_t)s0 * DD);
        acc0 = vmax8(acc0, u0);
    }

    h8u a;
    a.v = vmax8(vmax8(acc0, acc1), vmax8(acc2, acc3));
#pragma unroll
    for (int off = 16; off <= 32; off <<= 1) {
        h8u b;
#pragma unroll
        for (int c = 0; c < 4; ++c) b.i[c] = __shfl_xor(a.i[c], off);
        a.v = vmax8(a.v, b.v);
    }
    if (g == 0)
        *(f16x8*)(agg + (size_t)node * DD + l * 8) = a.v;
}

// ---------------- fp16 MFMA GEMM (round-9 best): 256 threads, 4 waves, mt=2 nt=8 ----
// EPI: 0 = none (f32 out), 1 = relu (half out), 2 = relu + row-L2-norm (f32 out + half copy)
template <int EPI, bool FUSED>
__global__ __launch_bounds__(256) void gemm_f16(
    const __half* __restrict__ A,    // fp16 [nrows][128]
    const __half* __restrict__ WA,   // swizzled fp16 [128][128]
    const __half* __restrict__ G,    // fp16 [nrows][128] (linear)
    const __half* __restrict__ WG,   // swizzled fp16 [128][128]
    const float* __restrict__ bias,
    float* __restrict__ outf, __half* __restrict__ outh, int nrows) {
    __shared__ __half Ws[DD * DD];   // 32 KB
    int tid = threadIdx.x;
    int lane = tid & 63;
    int w = tid >> 6;
    int l16 = lane & 15;
    int lg = lane >> 4;
    int rbase = blockIdx.x * 128 + w * 32;

    {
        const f32x4* src = (const f32x4*)(const void*)WA;
        f32x4* dst = (f32x4*)(void*)Ws;
#pragma unroll
        for (int i = 0; i < 8; ++i) dst[i * 256 + tid] = src[i * 256 + tid];
    }
    __syncthreads();

    int ar0 = min(rbase + l16, nrows - 1);
    int ar1 = min(rbase + 16 + l16, nrows - 1);
    size_t aoff0 = (size_t)ar0 * DD;
    size_t aoff1 = (size_t)ar1 * DD;

    f32x4 acc[2][8];
#pragma unroll
    for (int mt = 0; mt < 2; ++mt)
#pragma unroll
        for (int nt = 0; nt < 8; ++nt) acc[mt][nt] = (f32x4){0.f, 0.f, 0.f, 0.f};

    int swz = (l16 & 7) << 3;   // XOR in half-elements (16B groups)

    // ---- pass 1: A ----
#pragma unroll
    for (int kk = 0; kk < 4; ++kk) {
        int k0 = kk * 32 + lg * 8;
        f16x8 a0 = *(const f16x8*)(const void*)(A + aoff0 + k0);
        f16x8 a1 = *(const f16x8*)(const void*)(A + aoff1 + k0);
        int klds = k0 ^ swz;
#pragma unroll
        for (int nt = 0; nt < 8; ++nt) {
            f16x8 wh = *(const f16x8*)(const void*)(Ws + (nt * 16 + l16) * DD + klds);
            acc[0][nt] = __builtin_amdgcn_mfma_f32_16x16x32_f16(a0, wh, acc[0][nt], 0, 0, 0);
            acc[1][nt] = __builtin_amdgcn_mfma_f32_16x16x32_f16(a1, wh, acc[1][nt], 0, 0, 0);
        }
    }

    // ---- pass 2: G (restage WG into same LDS) ----
    if constexpr (FUSED) {
        __syncthreads();
        {
            const f32x4* src = (const f32x4*)(const void*)WG;
            f32x4* dst = (f32x4*)(void*)Ws;
#pragma unroll
            for (int i = 0; i < 8; ++i) dst[i * 256 + tid] = src[i * 256 + tid];
        }
        __syncthreads();
#pragma unroll
        for (int kk = 0; kk < 4; ++kk) {
            int k0 = kk * 32 + lg * 8;
            f16x8 g0 = *(const f16x8*)(const void*)(G + aoff0 + k0);
            f16x8 g1 = *(const f16x8*)(const void*)(G + aoff1 + k0);
            int klds = k0 ^ swz;
#pragma unroll
            for (int nt = 0; nt < 8; ++nt) {
                f16x8 uh = *(const f16x8*)(const void*)(Ws + (nt * 16 + l16) * DD + klds);
                acc[0][nt] = __builtin_amdgcn_mfma_f32_16x16x32_f16(g0, uh, acc[0][nt], 0, 0, 0);
                acc[1][nt] = __builtin_amdgcn_mfma_f32_16x16x32_f16(g1, uh, acc[1][nt], 0, 0, 0);
            }
        }
    }

    // ---- epilogue: direct fragment stores (row = rbase + mt*16 + lg*4 + r, col = nt*16+l16) ----
    float bv[8];
#pragma unroll
    for (int nt = 0; nt < 8; ++nt) bv[nt] = bias[nt * 16 + l16];

#pragma unroll
    for (int mt = 0; mt < 2; ++mt) {
#pragma unroll
        for (int r = 0; r < 4; ++r) {
            int row = rbase + mt * 16 + lg * 4 + r;
            float vv[8];
            float s = 0.f;
#pragma unroll
            for (int nt = 0; nt < 8; ++nt) {
                float v = acc[mt][nt][r] + bv[nt];
                if (EPI >= 1) v = fmaxf(v, 0.f);
                vv[nt] = v;
                s += v * v;
            }
            if constexpr (EPI == 2) {
                s += __shfl_xor(s, 1);
                s += __shfl_xor(s, 2);
                s += __shfl_xor(s, 4);
                s += __shfl_xor(s, 8);
                float sc = 1.0f / fmaxf(sqrtf(s), 1e-12f);
#pragma unroll
                for (int nt = 0; nt < 8; ++nt) vv[nt] *= sc;
            }
            if (row < nrows) {
                if constexpr (EPI == 1) {
#pragma unroll
                    for (int nt = 0; nt < 8; ++nt)
                        outh[(size_t)row * DD + nt * 16 + l16] = __float2half(vv[nt]);
                } else {
#pragma unroll
                    for (int nt = 0; nt < 8; ++nt)
                        outf[(size_t)row * DD + nt * 16 + l16] = vv[nt];
                    if (EPI == 2 && outh != nullptr) {
#pragma unroll
                        for (int nt = 0; nt < 8; ++nt)
                            outh[(size_t)row * DD + nt * 16 + l16] = __float2half(vv[nt]);
                    }
                }
            }
        }
    }
}

static inline size_t align16(size_t x) { return (x + 15) & ~(size_t)15; }

extern "C" void kernel_launch(void* const* d_in, const int* in_sizes, int n_in,
                              void* d_out, int out_size, void* d_ws, size_t ws_size,
                              hipStream_t stream) {
    const float* x  = (const float*)d_in[0];
    const int* esrc = (const int*)d_in[1];
    const int* edst = (const int*)d_in[2];
    const float* Wm[6];
    for (int i = 0; i < 6; ++i) Wm[i] = (const float*)d_in[3 + i];
    const float* bpool0 = (const float*)d_in[9];
    const float* b0     = (const float*)d_in[10];
    const float* bpool1 = (const float*)d_in[11];
    const float* b1     = (const float*)d_in[12];

    int N = in_sizes[0] / DD;
    int E = in_sizes[1];
    int NB = (N + BK_NODES - 1) >> BK_SHIFT;       // 782 buckets for N=50000
    int chunk = (E + NBLK - 1) / NBLK;             // edges per binning block
    int nh = NB * NBLK;                            // hist2d elements
    int nscan = (nh + SCAN_CHUNK - 1) / SCAN_CHUNK;

    // workspace layout
    char* p = (char*)d_ws;
    __half* Wh     = (__half*)p;   p += align16((size_t)6 * 16384 * 2);
    __half* xh     = (__half*)p;   p += align16((size_t)N * DD * 2);
    __half* ench   = (__half*)p;   p += align16((size_t)N * DD * 2);
    __half* m      = (__half*)p;   p += align16((size_t)N * DD * 2);
    __half* agg    = (__half*)p;   p += align16((size_t)N * DD * 2);
    int* hist2dA   = (int*)p;      p += align16((size_t)nh * 4);
    int* hist2dB   = (int*)p;      p += align16((size_t)nh * 4);
    int* bsum      = (int*)p;      p += align16((size_t)nscan * 4);
    int* rowptr    = (int*)p;      p += align16((size_t)(N + 1) * 4);
    int* es2       = (int*)p;      p += align16((size_t)E * 4);
    int* ed2       = (int*)p;      p += align16((size_t)E * 4);
    unsigned* ebuf = (unsigned*)p; p += align16((size_t)E * 4);
    int* csr_src   = (int*)p;      p += align16((size_t)E * 4);

    float* out_h   = (float*)d_out;                  // output 0: final layer
    float* out_enc = (float*)d_out + (size_t)N * DD; // output 1: enc_feat_input

    // prep: weights/x -> fp16
    prep_w<<<384, 256, 0, stream>>>(Wm[0], Wm[1], Wm[2], Wm[3], Wm[4], Wm[5], Wh);
    prep_x<<<(N * DD / 8 + 255) / 256, 256, 0, stream>>>(x, xh, N * DD / 8);

    // phase A: approx-sort edges by src (bucket granularity) for gather L2 locality
    hist2d_kernel<<<NBLK, 256, NB * 4, stream>>>(esrc, hist2dA, E, NB, chunk);
    partial_reduce<<<nscan, SCAN_T, 0, stream>>>(hist2dA, bsum, nh);
    scan_excl_inplace<<<nscan, SCAN_T, 0, stream>>>(hist2dA, bsum, nh);
    bin_src<<<NBLK, 256, NB * 4, stream>>>(esrc, edst, hist2dA, es2, ed2, E, NB, chunk);

    // phase B: CSR by dst over the src-ordered pairs
    hist2d_kernel<<<NBLK, 256, NB * 4, stream>>>(ed2, hist2dB, E, NB, chunk);
    partial_reduce<<<nscan, SCAN_T, 0, stream>>>(hist2dB, bsum, nh);
    scan_excl_inplace<<<nscan, SCAN_T, 0, stream>>>(hist2dB, bsum, nh);
    bin_edges2<<<NBLK, 256, NB * 4, stream>>>(es2, ed2, hist2dB, ebuf, E, NB, chunk);
    build_csr<<<NB, 256, 0, stream>>>(ebuf, hist2dB, rowptr, csr_src, N, NB, E);

    int gb = (N + 127) / 128;
    int sb = (N + 3) / 4;

    // layer 0
    gemm_f16<1, false><<<gb, 256, 0, stream>>>(xh, Wh + 0 * 16384, nullptr, nullptr,
                                               bpool0, nullptr, m, N);
    segmax2<<<sb, 256, 0, stream>>>(m, rowptr, csr_src, agg, N);
    gemm_f16<2, true><<<gb, 256, 0, stream>>>(xh, Wh + 1 * 16384, agg, Wh + 2 * 16384,
                                              b0, out_enc, ench, N);

    // layer 1
    gemm_f16<1, false><<<gb, 256, 0, stream>>>(ench, Wh + 3 * 16384, nullptr, nullptr,
                                               bpool1, nullptr, m, N);
    segmax2<<<sb, 256, 0, stream>>>(m, rowptr, csr_src, agg, N);
    gemm_f16<0, true><<<gb, 256, 0, stream>>>(ench, Wh + 4 * 16384, agg, Wh + 5 * 16384,
                                              b1, out_h, nullptr, N);
}

// Round 13
// 172.148 us; speedup vs baseline: 1.2553x; 1.2553x over previous
//
#include <hip/hip_runtime.h>
#include <hip/hip_fp16.h>

#define DD 128
#define BK_SHIFT 6
#define BK_NODES 64    // nodes per bucket
#define NBLK 256       // edge-chunk blocks for binning
#define SCAN_T 1024
#define SCAN_E 8
#define SCAN_CHUNK (SCAN_T * SCAN_E)   // 8192

typedef __attribute__((ext_vector_type(8))) _Float16 f16x8;
typedef __attribute__((ext_vector_type(4))) float f32x4;

union h8u { f16x8 v; int i[4]; };

static __device__ __forceinline__ f16x8 vmax8(f16x8 a, f16x8 b) {
#pragma unroll
    for (int i = 0; i < 8; ++i) a[i] = a[i] > b[i] ? a[i] : b[i];
    return a;
}

// ---------------- weights -> fp16, pre-swizzled for LDS bank-conflict-free reads ----
// Array layout: row j (output col), col k. Swizzle: k' = k ^ ((j&7)<<3)  (16B groups)
__global__ void prep_w(const float* __restrict__ W0, const float* __restrict__ W1,
                       const float* __restrict__ W2, const float* __restrict__ W3,
                       const float* __restrict__ W4, const float* __restrict__ W5,
                       __half* __restrict__ Wh) {
    int idx = blockIdx.x * 256 + threadIdx.x;   // 0 .. 6*16384-1
    int wi = idx >> 14;
    int off = idx & 16383;
    int j = off >> 7;
    int k = off & 127;
    float a;
    switch (wi) {
        case 0: a = W0[off]; break;
        case 1: a = W1[off]; break;
        case 2: a = W2[off]; break;
        case 3: a = W3[off]; break;
        case 4: a = W4[off]; break;
        default: a = W5[off]; break;
    }
    int k2 = k ^ ((j & 7) << 3);
    Wh[(size_t)wi * 16384 + j * DD + k2] = __float2half(a);
}

// ---------------- x (f32) -> fp16, vectorized ----------------
__global__ void prep_x(const float* __restrict__ x, __half* __restrict__ xh, int n8) {
    int i = blockIdx.x * 256 + threadIdx.x;
    if (i >= n8) return;
    float4 u0 = *(const float4*)(x + (size_t)i * 8);
    float4 u1 = *(const float4*)(x + (size_t)i * 8 + 4);
    f16x8 v;
    v[0] = (_Float16)u0.x; v[1] = (_Float16)u0.y; v[2] = (_Float16)u0.z; v[3] = (_Float16)u0.w;
    v[4] = (_Float16)u1.x; v[5] = (_Float16)u1.y; v[6] = (_Float16)u1.z; v[7] = (_Float16)u1.w;
    *(f16x8*)(xh + (size_t)i * 8) = v;
}

// ---------------- CSR stage 1: per-(bucket,block) histogram, LDS only ----------------
__global__ __launch_bounds__(256) void hist2d_kernel(const int* __restrict__ dst,
                                                     int* __restrict__ hist2d,
                                                     int E, int NB, int chunk) {
    extern __shared__ int h[];   // NB ints
    int t = threadIdx.x, b = blockIdx.x;
    for (int i = t; i < NB; i += 256) h[i] = 0;
    __syncthreads();
    int e0 = b * chunk, e1 = min(e0 + chunk, E);
    for (int e = e0 + t; e < e1; e += 256)
        atomicAdd(&h[dst[e] >> BK_SHIFT], 1);
    __syncthreads();
    for (int i = t; i < NB; i += 256) hist2d[i * NBLK + b] = h[i];
}

// ---------------- CSR stage 2: multi-block exclusive scan, in place ----------------
__global__ __launch_bounds__(SCAN_T) void partial_reduce(const int* __restrict__ data,
                                                         int* __restrict__ bsum, int n) {
    __shared__ int s[SCAN_T];
    int t = threadIdx.x;
    int i0 = blockIdx.x * SCAN_CHUNK + t * SCAN_E;
    int sum = 0;
#pragma unroll
    for (int u = 0; u < SCAN_E; ++u) {
        int i = i0 + u;
        sum += (i < n) ? data[i] : 0;
    }
    s[t] = sum;
    __syncthreads();
    for (int off = SCAN_T / 2; off > 0; off >>= 1) {
        if (t < off) s[t] += s[t + off];
        __syncthreads();
    }
    if (t == 0) bsum[blockIdx.x] = s[0];
}

__global__ __launch_bounds__(SCAN_T) void scan_excl_inplace(int* __restrict__ data,
                                                            const int* __restrict__ bsum, int n) {
    __shared__ int s[SCAN_T];
    int t = threadIdx.x;
    int b = blockIdx.x;
    int carry = 0;
    for (int k = 0; k < b; ++k) carry += bsum[k];   // few blocks; cheap, uniform
    int i0 = b * SCAN_CHUNK + t * SCAN_E;
    int v[SCAN_E];
    int sum = 0;
#pragma unroll
    for (int u = 0; u < SCAN_E; ++u) {
        v[u] = (i0 + u < n) ? data[i0 + u] : 0;
        sum += v[u];
    }
    s[t] = sum;
    __syncthreads();
    for (int off = 1; off < SCAN_T; off <<= 1) {
        int x = (t >= off) ? s[t - off] : 0;
        __syncthreads();
        s[t] += x;
        __syncthreads();
    }
    int run = s[t] - sum + carry;   // exclusive prefix of this thread's first elem
#pragma unroll
    for (int u = 0; u < SCAN_E; ++u) {
        int i = i0 + u;
        if (i < n) {
            data[i] = run;
            run += v[u];
        }
    }
}

// ---------------- CSR stage 3: bin edges via LDS cursors (no global atomics) ----------------
__global__ __launch_bounds__(256) void bin_edges2(const int* __restrict__ src,
                                                  const int* __restrict__ dst,
                                                  const int* __restrict__ base,   // scanned hist2d
                                                  unsigned* __restrict__ ebuf,
                                                  int E, int NB, int chunk) {
    extern __shared__ int h[];   // NB cursors
    int t = threadIdx.x, b = blockIdx.x;
    for (int i = t; i < NB; i += 256) h[i] = base[i * NBLK + b];
    __syncthreads();
    int e0 = b * chunk, e1 = min(e0 + chunk, E);
    for (int e = e0 + t; e < e1; e += 256) {
        int d = dst[e];
        int p = atomicAdd(&h[d >> BK_SHIFT], 1);
        ebuf[p] = ((unsigned)src[e] << BK_SHIFT) | (unsigned)(d & (BK_NODES - 1));
    }
}

// ---------------- CSR stage 4: per-bucket rowptr + csr scatter ----------------
__global__ __launch_bounds__(256) void build_csr(const unsigned* __restrict__ ebuf,
                                                 const int* __restrict__ base,
                                                 int* __restrict__ rowptr,
                                                 int* __restrict__ csr_src, int N, int NB, int E) {
    __shared__ int cnt[BK_NODES];
    __shared__ int cur[BK_NODES];
    int b = blockIdx.x;
    int t = threadIdx.x;
    int beg = base[b * NBLK];
    int end = (b == NB - 1) ? E : base[(b + 1) * NBLK];
    if (b == 0 && t == 0) rowptr[0] = 0;
    if (t < BK_NODES) cnt[t] = 0;
    __syncthreads();
    for (int e = beg + t; e < end; e += 256)
        atomicAdd(&cnt[ebuf[e] & (BK_NODES - 1)], 1);
    __syncthreads();
    if (t < 64) {   // one wave: scan 64 counts
        int v = cnt[t];
        int inc = v;
#pragma unroll
        for (int off = 1; off < 64; off <<= 1) {
            int x = __shfl_up(inc, off);
            if (t >= off) inc += x;
        }
        cur[t] = beg + inc - v;          // exclusive
        int node = b * BK_NODES + t;
        if (node < N) rowptr[node + 1] = beg + inc;
    }
    __syncthreads();
    for (int e = beg + t; e < end; e += 256) {
        unsigned v = ebuf[e];
        int p = atomicAdd(&cur[v & (BK_NODES - 1)], 1);
        csr_src[p] = (int)(v >> BK_SHIFT);
    }
}

// ---------------- segment max gather v2: 4 edge-subgroups x 16 col-chunks ----------------
// One wave per node. Lane = 16*g + l: subgroup g handles edges beg+g, beg+g+4, ...;
// lane loads 16B (8 halves) of its row -> one load instruction covers 4 edges (1KB).
// 4 rotating accumulators -> 16 edges in flight. Packed fp16 max; exact (max = select).
__global__ __launch_bounds__(256) void segmax2(const __half* __restrict__ m,
                                               const int* __restrict__ rowptr,
                                               const int* __restrict__ csr_src,
                                               __half* __restrict__ agg, int n) {
    int node = blockIdx.x * 4 + (threadIdx.x >> 6);
    if (node >= n) return;
    int lane = threadIdx.x & 63;
    int g = lane >> 4;
    int l = lane & 15;
    int beg = rowptr[node], end = rowptr[node + 1];
    const __half* mp = m + l * 8;

    f16x8 acc0 = (f16x8)0, acc1 = (f16x8)0, acc2 = (f16x8)0, acc3 = (f16x8)0;  // relu'd >= 0

    int e = beg + g;
    for (; e + 12 < end; e += 16) {
        int s0 = csr_src[e];
        int s1 = csr_src[e + 4];
        int s2 = csr_src[e + 8];
        int s3 = csr_src[e + 12];
        f16x8 u0 = *(const f16x8*)(mp + (size_t)s0 * DD);
        f16x8 u1 = *(const f16x8*)(mp + (size_t)s1 * DD);
        f16x8 u2 = *(const f16x8*)(mp + (size_t)s2 * DD);
        f16x8 u3 = *(const f16x8*)(mp + (size_t)s3 * DD);
        acc0 = vmax8(acc0, u0);
        acc1 = vmax8(acc1, u1);
        acc2 = vmax8(acc2, u2);
        acc3 = vmax8(acc3, u3);
    }
    for (; e < end; e += 4) {
        int s0 = csr_src[e];
        f16x8 u0 = *(const f16x8*)(mp + (size_t)s0 * DD);
        acc0 = vmax8(acc0, u0);
    }

    h8u a;
    a.v = vmax8(vmax8(acc0, acc1), vmax8(acc2, acc3));
    // combine across the 4 subgroups (lanes differing in bits 4,5)
#pragma unroll
    for (int off = 16; off <= 32; off <<= 1) {
        h8u b;
#pragma unroll
        for (int c = 0; c < 4; ++c) b.i[c] = __shfl_xor(a.i[c], off);
        a.v = vmax8(a.v, b.v);
    }
    if (g == 0)
        *(f16x8*)(agg + (size_t)node * DD + l * 8) = a.v;
}

// ---------------- fp16 MFMA GEMM (best config): 256 threads, 4 waves, mt=2 nt=8 ----
// W staged in LDS (pre-swizzled source -> linear copy -> XOR'd ds_read, conflict-free).
// f32 outputs (never re-read on device) use non-temporal stores to avoid polluting
// L2/L3 that the segmax gather needs for m/agg residency.
// EPI: 0 = none (f32 out), 1 = relu (half out), 2 = relu + row-L2-norm (f32 out + half copy)
template <int EPI, bool FUSED>
__global__ __launch_bounds__(256) void gemm_f16(
    const __half* __restrict__ A,    // fp16 [nrows][128]
    const __half* __restrict__ WA,   // swizzled fp16 [128][128]
    const __half* __restrict__ G,    // fp16 [nrows][128] (linear)
    const __half* __restrict__ WG,   // swizzled fp16 [128][128]
    const float* __restrict__ bias,
    float* __restrict__ outf, __half* __restrict__ outh, int nrows) {
    __shared__ __half Ws[DD * DD];   // 32 KB
    int tid = threadIdx.x;
    int lane = tid & 63;
    int w = tid >> 6;
    int l16 = lane & 15;
    int lg = lane >> 4;
    int rbase = blockIdx.x * 128 + w * 32;

    {
        const f32x4* src = (const f32x4*)(const void*)WA;
        f32x4* dst = (f32x4*)(void*)Ws;
#pragma unroll
        for (int i = 0; i < 8; ++i) dst[i * 256 + tid] = src[i * 256 + tid];
    }
    __syncthreads();

    int ar0 = min(rbase + l16, nrows - 1);
    int ar1 = min(rbase + 16 + l16, nrows - 1);
    size_t aoff0 = (size_t)ar0 * DD;
    size_t aoff1 = (size_t)ar1 * DD;

    f32x4 acc[2][8];
#pragma unroll
    for (int mt = 0; mt < 2; ++mt)
#pragma unroll
        for (int nt = 0; nt < 8; ++nt) acc[mt][nt] = (f32x4){0.f, 0.f, 0.f, 0.f};

    int swz = (l16 & 7) << 3;   // XOR in half-elements (16B groups)

    // ---- pass 1: A ----
#pragma unroll
    for (int kk = 0; kk < 4; ++kk) {
        int k0 = kk * 32 + lg * 8;
        f16x8 a0 = *(const f16x8*)(const void*)(A + aoff0 + k0);
        f16x8 a1 = *(const f16x8*)(const void*)(A + aoff1 + k0);
        int klds = k0 ^ swz;
#pragma unroll
        for (int nt = 0; nt < 8; ++nt) {
            f16x8 wh = *(const f16x8*)(const void*)(Ws + (nt * 16 + l16) * DD + klds);
            acc[0][nt] = __builtin_amdgcn_mfma_f32_16x16x32_f16(a0, wh, acc[0][nt], 0, 0, 0);
            acc[1][nt] = __builtin_amdgcn_mfma_f32_16x16x32_f16(a1, wh, acc[1][nt], 0, 0, 0);
        }
    }

    // ---- pass 2: G (restage WG into same LDS) ----
    if constexpr (FUSED) {
        __syncthreads();
        {
            const f32x4* src = (const f32x4*)(const void*)WG;
            f32x4* dst = (f32x4*)(void*)Ws;
#pragma unroll
            for (int i = 0; i < 8; ++i) dst[i * 256 + tid] = src[i * 256 + tid];
        }
        __syncthreads();
#pragma unroll
        for (int kk = 0; kk < 4; ++kk) {
            int k0 = kk * 32 + lg * 8;
            f16x8 g0 = *(const f16x8*)(const void*)(G + aoff0 + k0);
            f16x8 g1 = *(const f16x8*)(const void*)(G + aoff1 + k0);
            int klds = k0 ^ swz;
#pragma unroll
            for (int nt = 0; nt < 8; ++nt) {
                f16x8 uh = *(const f16x8*)(const void*)(Ws + (nt * 16 + l16) * DD + klds);
                acc[0][nt] = __builtin_amdgcn_mfma_f32_16x16x32_f16(g0, uh, acc[0][nt], 0, 0, 0);
                acc[1][nt] = __builtin_amdgcn_mfma_f32_16x16x32_f16(g1, uh, acc[1][nt], 0, 0, 0);
            }
        }
    }

    // ---- epilogue: direct fragment stores (row = rbase + mt*16 + lg*4 + r, col = nt*16+l16) ----
    float bv[8];
#pragma unroll
    for (int nt = 0; nt < 8; ++nt) bv[nt] = bias[nt * 16 + l16];

#pragma unroll
    for (int mt = 0; mt < 2; ++mt) {
#pragma unroll
        for (int r = 0; r < 4; ++r) {
            int row = rbase + mt * 16 + lg * 4 + r;
            float vv[8];
            float s = 0.f;
#pragma unroll
            for (int nt = 0; nt < 8; ++nt) {
                float v = acc[mt][nt][r] + bv[nt];
                if (EPI >= 1) v = fmaxf(v, 0.f);
                vv[nt] = v;
                s += v * v;
            }
            if constexpr (EPI == 2) {
                s += __shfl_xor(s, 1);
                s += __shfl_xor(s, 2);
                s += __shfl_xor(s, 4);
                s += __shfl_xor(s, 8);
                float sc = 1.0f / fmaxf(sqrtf(s), 1e-12f);
#pragma unroll
                for (int nt = 0; nt < 8; ++nt) vv[nt] *= sc;
            }
            if (row < nrows) {
                if constexpr (EPI == 1) {
#pragma unroll
                    for (int nt = 0; nt < 8; ++nt)
                        outh[(size_t)row * DD + nt * 16 + l16] = __float2half(vv[nt]);
                } else {
                    // f32 output is never re-read on device -> non-temporal
#pragma unroll
                    for (int nt = 0; nt < 8; ++nt)
                        __builtin_nontemporal_store(vv[nt], &outf[(size_t)row * DD + nt * 16 + l16]);
                    if (EPI == 2 && outh != nullptr) {
#pragma unroll
                        for (int nt = 0; nt < 8; ++nt)
                            outh[(size_t)row * DD + nt * 16 + l16] = __float2half(vv[nt]);
                    }
                }
            }
        }
    }
}

static inline size_t align16(size_t x) { return (x + 15) & ~(size_t)15; }

extern "C" void kernel_launch(void* const* d_in, const int* in_sizes, int n_in,
                              void* d_out, int out_size, void* d_ws, size_t ws_size,
                              hipStream_t stream) {
    const float* x  = (const float*)d_in[0];
    const int* esrc = (const int*)d_in[1];
    const int* edst = (const int*)d_in[2];
    const float* Wm[6];
    for (int i = 0; i < 6; ++i) Wm[i] = (const float*)d_in[3 + i];
    const float* bpool0 = (const float*)d_in[9];
    const float* b0     = (const float*)d_in[10];
    const float* bpool1 = (const float*)d_in[11];
    const float* b1     = (const float*)d_in[12];

    int N = in_sizes[0] / DD;
    int E = in_sizes[1];
    int NB = (N + BK_NODES - 1) >> BK_SHIFT;       // 782 buckets for N=50000
    int chunk = (E + NBLK - 1) / NBLK;             // edges per binning block
    int nh = NB * NBLK;                            // hist2d elements
    int nscan = (nh + SCAN_CHUNK - 1) / SCAN_CHUNK;

    // workspace layout
    char* p = (char*)d_ws;
    __half* Wh     = (__half*)p;   p += align16((size_t)6 * 16384 * 2);
    __half* xh     = (__half*)p;   p += align16((size_t)N * DD * 2);
    __half* ench   = (__half*)p;   p += align16((size_t)N * DD * 2);
    __half* m      = (__half*)p;   p += align16((size_t)N * DD * 2);
    __half* agg    = (__half*)p;   p += align16((size_t)N * DD * 2);
    int* hist2d    = (int*)p;      p += align16((size_t)nh * 4);
    int* bsum      = (int*)p;      p += align16((size_t)nscan * 4);
    int* rowptr    = (int*)p;      p += align16((size_t)(N + 1) * 4);
    unsigned* ebuf = (unsigned*)p; p += align16((size_t)E * 4);
    int* csr_src   = (int*)p;      p += align16((size_t)E * 4);

    float* out_h   = (float*)d_out;                  // output 0: final layer
    float* out_enc = (float*)d_out + (size_t)N * DD; // output 1: enc_feat_input

    // prep: weights/x -> fp16 + CSR by dst (bucketed, atomic-free binning)
    prep_w<<<384, 256, 0, stream>>>(Wm[0], Wm[1], Wm[2], Wm[3], Wm[4], Wm[5], Wh);
    prep_x<<<(N * DD / 8 + 255) / 256, 256, 0, stream>>>(x, xh, N * DD / 8);
    hist2d_kernel<<<NBLK, 256, NB * 4, stream>>>(edst, hist2d, E, NB, chunk);
    partial_reduce<<<nscan, SCAN_T, 0, stream>>>(hist2d, bsum, nh);
    scan_excl_inplace<<<nscan, SCAN_T, 0, stream>>>(hist2d, bsum, nh);
    bin_edges2<<<NBLK, 256, NB * 4, stream>>>(esrc, edst, hist2d, ebuf, E, NB, chunk);
    build_csr<<<NB, 256, 0, stream>>>(ebuf, hist2d, rowptr, csr_src, N, NB, E);

    int gb = (N + 127) / 128;
    int sb = (N + 3) / 4;

    // layer 0
    gemm_f16<1, false><<<gb, 256, 0, stream>>>(xh, Wh + 0 * 16384, nullptr, nullptr,
                                               bpool0, nullptr, m, N);
    segmax2<<<sb, 256, 0, stream>>>(m, rowptr, csr_src, agg, N);
    gemm_f16<2, true><<<gb, 256, 0, stream>>>(xh, Wh + 1 * 16384, agg, Wh + 2 * 16384,
                                              b0, out_enc, ench, N);

    // layer 1
    gemm_f16<1, false><<<gb, 256, 0, stream>>>(ench, Wh + 3 * 16384, nullptr, nullptr,
                                               bpool1, nullptr, m, N);
    segmax2<<<sb, 256, 0, stream>>>(m, rowptr, csr_src, agg, N);
    gemm_f16<0, true><<<gb, 256, 0, stream>>>(ench, Wh + 4 * 16384, agg, Wh + 5 * 16384,
                                              b1, out_h, nullptr, N);
}